// Round 7
// baseline (142.540 us; speedup 1.0000x reference)
//
#include <hip/hip_runtime.h>

// SSIM loss over [8,8,3,256,256] fp32.
// Packed-FP16 convolutions (v_pk_fma_f16), fp32 epilogue.
// R13: full unroll (ring->SSA, rule-#20 fix) + sum/diff channels. 60.6us.
// R14 REGRESSION: DPP shifts (wait-state hazards; bpermute runs on the
//      concurrent DS pipe -- keeper).
// R15: branchless clamped loads + 2-deep prefetch. band 52.7us, busy 65%.
//      Issue-bound: 3425 instr/wave, busy-time 34.3us == 65% of 52.7.
// R16: LDS halo-sharing redesign. Old: every wave register-ring-staged its
//      own 10-row halo (25% of all instrs; 3.5x redundant loads; 44-reg
//      ring). New: block = 16 output rows; 4 waves cooperatively stage all
//      26 halo rows ONCE into LDS as packed fp16 {s,d} (26KB), one barrier,
//      then each wave computes 4 rows via 11x ds_read_b128 (one read/tap,
//      taps via compile-time offset:k*1024; lanes stride 16B = standard
//      conflict-free b128 pattern). Ring/shift/preload/prefetch deleted.
//      Static ~1800 instr/wave -> busy floor ~18us; LDS allows 6 blocks/CU
//      -> 6 waves/SIMD resident (vs 3.4 measured at R15).
// R9 scar: cvt_pkrtz returns half2 directly -- bit-cast, don't assign to v2f.

typedef _Float16 h2 __attribute__((ext_vector_type(2)));
typedef __fp16 fp16v2 __attribute__((ext_vector_type(2)));

#define WSZ 11
#define RAD 5
#define IMH 256
#define IMW 256
#define BROWS 16                     // output rows per block
#define HROWS (BROWS + 2 * RAD)      // 26 staged rows
#define NBANDS (IMH / BROWS)         // 16
#define NPLANES 192                  // 8*8*3
#define NGRID (NPLANES * NBANDS)     // 3072 blocks
#define WPB 4                        // waves per block
#define RPW (BROWS / WPB)            // 4 output rows per wave
#define NPIXF (192.0f * 256.0f * 256.0f)

// Gaussian(sigma=1.5, ws=11) weights, normalized.
#define GW0 0.001028381f
#define GW1 0.007598770f
#define GW2 0.036000770f
#define GW3 0.109360600f
#define GW4 0.213005700f
#define GW5 0.266011790f

// ---- packed fp16 ops (full-rate VOP3P) ----
__device__ __forceinline__ h2 pk_fma16(h2 a, h2 b, h2 c) {
    h2 d;
    asm("v_pk_fma_f16 %0, %1, %2, %3" : "=v"(d) : "v"(a), "v"(b), "v"(c));
    return d;
}
__device__ __forceinline__ h2 pk_mul16(h2 a, h2 b) {
    h2 d;
    asm("v_pk_mul_f16 %0, %1, %2" : "=v"(d) : "v"(a), "v"(b));
    return d;
}
__device__ __forceinline__ h2 pk_add16(h2 a, h2 b) {
    h2 d;
    asm("v_pk_add_f16 %0, %1, %2" : "=v"(d) : "v"(a), "v"(b));
    return d;
}
__device__ __forceinline__ h2 pk_min16(h2 a, h2 b) {
    h2 d;
    asm("v_pk_min_f16 %0, %1, %2" : "=v"(d) : "v"(a), "v"(b));
    return d;
}
__device__ __forceinline__ h2 pk_max16(h2 a, h2 b) {
    h2 d;
    asm("v_pk_max_f16 %0, %1, %2" : "=v"(d) : "v"(a), "v"(b));
    return d;
}

union H2U { h2 h; unsigned u; };
__device__ __forceinline__ unsigned h2u(h2 v) { H2U x; x.h = v; return x.u; }
__device__ __forceinline__ h2 u2h(unsigned v) { H2U x; x.u = v; return x.h; }

// raw lane gather: src lane index precomputed (byte addr = lane*4)
__device__ __forceinline__ h2 bperm(int idx, h2 v) {
    return u2h((unsigned)__builtin_amdgcn_ds_bpermute(idx, (int)h2u(v)));
}
// {lo.h1, hi.h0}
__device__ __forceinline__ h2 albt(h2 hi, h2 lo) {
    return u2h(__builtin_amdgcn_alignbit(h2u(hi), h2u(lo), 16));
}

__device__ __forceinline__ h2 splat16(float s) {
    _Float16 t = (_Float16)s;
    return (h2){t, t};
}
__device__ __forceinline__ h2 zero16() { return (h2){(_Float16)0, (_Float16)0}; }

// pack two floats to half2 (v_cvt_pkrtz_f16_f32), clamp to [0,1] in fp16
// (equivalent to fp32-clamp-then-cvt for this data; 3 ops vs 5).
__device__ __forceinline__ h2 clip_pack(float a, float b, h2 Z, h2 O) {
    fp16v2 r = __builtin_amdgcn_cvt_pkrtz(a, b);
    h2 v = __builtin_bit_cast(h2, r);
    return pk_min16(pk_max16(v, Z), O);
}

__global__ __launch_bounds__(256, 4) void ssim_band_kernel(
    const float* __restrict__ pred,
    const float* __restrict__ targ,
    float* __restrict__ partial)
{
    const int tid = threadIdx.x;
    const int lane = tid & 63;
    const int wid = tid >> 6;              // 4 waves per block
    const int blk = blockIdx.x;
    const int plane = blk >> 4;            // 16 bands per plane
    const int band = blk & 15;
    const int r0 = band * BROWS;

    const float4* __restrict__ pp =
        (const float4*)(pred + (size_t)plane * (IMH * IMW));
    const float4* __restrict__ tp =
        (const float4*)(targ + (size_t)plane * (IMH * IMW));

    const h2 W0 = splat16(GW0), W1 = splat16(GW1), W2 = splat16(GW2),
             W3 = splat16(GW3), W4 = splat16(GW4), W5 = splat16(GW5);
    const h2 wv16[WSZ] = {W0, W1, W2, W3, W4, W5, W4, W3, W2, W1, W0};
    const h2 M2 = splat16(-2.0f);
    const h2 Z16 = zero16();
    const h2 O16 = splat16(1.0f);

    // Shared halo: 26 rows x 64 lanes x 16B = 26KB.
    // Each uint4 = {s01, d01, s23, d23} packed fp16 for 4 columns.
    __shared__ uint4 lds[HROWS * 64];
    __shared__ float wsum[WPB];

    // ---- Cooperative stage: 26 halo rows, once per block. ----
    // Branchless: clamped row address; OOB rows written as zeros (== the
    // reference's zero-padding).
    for (int j = wid; j < HROWS; j += WPB) {
        const int r = r0 - RAD + j;
        const int rc = min(max(r, 0), IMH - 1);
        const bool oob = (r < 0) | (r >= IMH);
        const float4 a = pp[rc * 64 + lane];
        const float4 c = tp[rc * 64 + lane];
        const h2 x0 = clip_pack(a.x, a.y, Z16, O16);
        const h2 x1 = clip_pack(a.z, a.w, Z16, O16);
        const h2 y0 = clip_pack(c.x, c.y, Z16, O16);
        const h2 y1 = clip_pack(c.z, c.w, Z16, O16);
        const h2 s0 = pk_add16(x0, y0);
        const h2 s1 = pk_add16(x1, y1);
        const h2 d0 = pk_fma16(M2, y0, s0);   // s - 2y = x - y
        const h2 d1 = pk_fma16(M2, y1, s1);
        uint4 w;
        w.x = oob ? 0u : h2u(s0);
        w.y = oob ? 0u : h2u(d0);
        w.z = oob ? 0u : h2u(s1);
        w.w = oob ? 0u : h2u(d1);
        lds[j * 64 + lane] = w;
    }
    __syncthreads();

    // Hoisted shuffle machinery: 4 index vectors + 4 edge predicates.
    const int iu1 = (lane - 1) << 2;
    const int iu2 = (lane - 2) << 2;
    const int id1 = (lane + 1) << 2;
    const int id2 = (lane + 2) << 2;
    const bool mu1 = lane >= 1;
    const bool mu2 = lane >= 2;
    const bool md1 = lane <= 62;
    const bool md2 = lane <= 61;

    const float C1 = 1e-4f, C2 = 9e-4f;
    float lsum = 0.f;

    // ---- Each wave computes RPW=4 output rows from shared LDS. ----
#pragma unroll
    for (int i = 0; i < RPW; ++i) {
        const int jb = wid * RPW + i;      // LDS row of tap k=0

        // Vertical pass: 11 x ds_read_b128 (tap offsets fold to imm) +
        // 4 channels {s, d, s^2, d^2} x 2 col-pairs.
        h2 vd[4][2];
#pragma unroll
        for (int p = 0; p < 2; ++p) {
            vd[0][p] = zero16(); vd[1][p] = zero16();
            vd[2][p] = zero16(); vd[3][p] = zero16();
        }
#pragma unroll
        for (int k = 0; k < WSZ; ++k) {
            const uint4 v = lds[(jb + k) * 64 + lane];
            const h2 wk = wv16[k];
            const h2 sA = u2h(v.x), dA = u2h(v.y);
            const h2 sB = u2h(v.z), dB = u2h(v.w);
            h2 ws = pk_mul16(wk, sA);
            h2 wd = pk_mul16(wk, dA);
            vd[0][0] = pk_add16(vd[0][0], ws);
            vd[1][0] = pk_add16(vd[1][0], wd);
            vd[2][0] = pk_fma16(ws, sA, vd[2][0]);
            vd[3][0] = pk_fma16(wd, dA, vd[3][0]);
            ws = pk_mul16(wk, sB);
            wd = pk_mul16(wk, dB);
            vd[0][1] = pk_add16(vd[0][1], ws);
            vd[1][1] = pk_add16(vd[1][1], wd);
            vd[2][1] = pk_fma16(ws, sB, vd[2][1]);
            vd[3][1] = pk_fma16(wd, dB, vd[3][1]);
        }

        // Horizontal pass per channel (R13/R15 keeper): 6 bpermutes (DS
        // pipe, overlaps VALU) + 6 edge guards + 7 alignbits + 22 pk ops.
        h2 hf[4][2];
#pragma unroll
        for (int ch = 0; ch < 4; ++ch) {
            const h2 H0 = vd[ch][0], H1 = vd[ch][1];
            h2 Gm3 = bperm(iu2, H1);      // {v-1, v0}
            h2 Gm2 = bperm(iu1, H0);      // {v1, v2}
            h2 Gm1 = bperm(iu1, H1);      // {v3, v4}
            h2 G2  = bperm(id1, H0);      // {v9, v10}
            h2 G3  = bperm(id1, H1);      // {v11, v12}
            h2 G4  = bperm(id2, H0);      // {v13, v14}
            Gm3 = mu2 ? Gm3 : zero16();
            Gm2 = mu1 ? Gm2 : zero16();
            Gm1 = mu1 ? Gm1 : zero16();
            G2  = md1 ? G2  : zero16();
            G3  = md1 ? G3  : zero16();
            G4  = md2 ? G4  : zero16();
            // Consecutive pairs P_k = {v[k], v[k+1]}.
            const h2 P0  = albt(Gm2, Gm3);
            const h2 P1  = Gm2;
            const h2 P2  = albt(Gm1, Gm2);
            const h2 P3  = Gm1;
            const h2 P4  = albt(H0, Gm1);
            const h2 P5  = H0;
            const h2 P6  = albt(H1, H0);
            const h2 P7  = H1;
            const h2 P8  = albt(G2, H1);
            const h2 P9  = G2;
            const h2 P10 = albt(G3, G2);
            const h2 P11 = G3;
            const h2 P12 = albt(G4, G3);
            // out pair {c0,c1} = sum_k w[k] * P_k
            h2 a0 = pk_mul16(W0, P0);
            a0 = pk_fma16(W1, P1, a0);
            a0 = pk_fma16(W2, P2, a0);
            a0 = pk_fma16(W3, P3, a0);
            a0 = pk_fma16(W4, P4, a0);
            a0 = pk_fma16(W5, P5, a0);
            a0 = pk_fma16(W4, P6, a0);
            a0 = pk_fma16(W3, P7, a0);
            a0 = pk_fma16(W2, P8, a0);
            a0 = pk_fma16(W1, P9, a0);
            a0 = pk_fma16(W0, P10, a0);
            // out pair {c2,c3} = sum_k w[k] * P_{k+2}
            h2 a1 = pk_mul16(W0, P2);
            a1 = pk_fma16(W1, P3, a1);
            a1 = pk_fma16(W2, P4, a1);
            a1 = pk_fma16(W3, P5, a1);
            a1 = pk_fma16(W4, P6, a1);
            a1 = pk_fma16(W5, P7, a1);
            a1 = pk_fma16(W4, P8, a1);
            a1 = pk_fma16(W3, P9, a1);
            a1 = pk_fma16(W2, P10, a1);
            a1 = pk_fma16(W1, P11, a1);
            a1 = pk_fma16(W0, P12, a1);
            hf[ch][0] = a0;
            hf[ch][1] = a1;
        }

        // SSIM epilogue in fp32 from sum/diff moments.
        // ms=G*s, md=G*d, Ss=G*s^2, Sd=G*d^2.
#pragma unroll
        for (int p = 0; p < 2; ++p) {
#pragma unroll
            for (int e = 0; e < 2; ++e) {
                const float ms = (float)hf[0][p][e];
                const float md = (float)hf[1][p][e];
                const float Ss = (float)hf[2][p][e];
                const float Sd = (float)hf[3][p][e];
                const float P = ms * ms, Q = md * md;
                const float mxy2 = 0.5f * (P - Q);          // 2*mx*my
                const float m2s  = 0.5f * (P + Q);          // mx^2+my^2
                const float Ssum = 0.5f * (Ss + Sd);        // Sxx+Syy
                const float ssum = fmaxf(Ssum - m2s, 0.f);  // vx+vy (joint clamp)
                const float sxy2 = fmaf(0.5f, Ss - Sd, -mxy2); // 2*sigma_xy
                const float num = (mxy2 + C1) * (sxy2 + C2);
                const float den = fmaf(m2s + C1, ssum + C2, 1e-8f);
                lsum += num * __builtin_amdgcn_rcpf(den);
            }
        }
    }

    // Wave reduction (64 lanes), then 4-wave LDS combine -> one store/block.
#pragma unroll
    for (int off = 32; off > 0; off >>= 1)
        lsum += __shfl_xor(lsum, off, 64);

    if (lane == 0) wsum[wid] = lsum;
    __syncthreads();
    if (tid == 0)
        partial[blk] = wsum[0] + wsum[1] + wsum[2] + wsum[3];
}

__global__ __launch_bounds__(256) void ssim_finalize(
    const float* __restrict__ partial,
    float* __restrict__ out)
{
    __shared__ float wsum[4];
    const int t = threadIdx.x;  // 256 threads
    float s = 0.f;
    for (int i = t; i < NGRID; i += 256) s += partial[i];
#pragma unroll
    for (int off = 32; off > 0; off >>= 1)
        s += __shfl_xor(s, off, 64);
    const int lane = t & 63, wv = t >> 6;
    if (lane == 0) wsum[wv] = s;
    __syncthreads();
    if (t == 0)
        out[0] = 1.0f - (wsum[0] + wsum[1] + wsum[2] + wsum[3]) / NPIXF;
}

extern "C" void kernel_launch(void* const* d_in, const int* in_sizes, int n_in,
                              void* d_out, int out_size, void* d_ws, size_t ws_size,
                              hipStream_t stream) {
    const float* pred = (const float*)d_in[0];
    const float* targ = (const float*)d_in[1];
    float* out = (float*)d_out;
    float* part = (float*)d_ws;    // 3072 floats = 12 KB scratch

    ssim_band_kernel<<<NGRID, 256, 0, stream>>>(pred, targ, part);
    ssim_finalize<<<1, 256, 0, stream>>>(part, out);
}